// Round 4
// baseline (402.100 us; speedup 1.0000x reference)
//
#include <hip/hip_runtime.h>
#include <stdint.h>

#define NBATCH   8
#define NA       1047552
#define PRE_NMS  6000
#define NPROP    1000
#define BINS     2048
#define HB       64         // histogram blocks per batch
#define GB       128        // gather blocks per batch
#define CAND_CAP 8192
#define NMS_THR  0.7f
#define GBUF     1024       // per-block LDS candidate buffer
#define SCAP     2048       // per-bin sort capacity
#define PCHUNK   32         // pair-list chunks per batch (keyed by j>>8; 24 used)
#define PCAP     256        // pairs per chunk
#define REJW     192        // 6144-bit rejected bitset words (24 chunks * 8 words)
#define PTI      64         // k_pairs i-tile (LDS)
#define PTJ      1024       // k_pairs j-tile (JR regs/thread * 256 threads)
#define JR       4          // j-boxes per thread

// ---- workspace layout (bytes) ---- (identical to the verified round-1 layout;
// OFF_HIST region now unused but kept so WS_NEEDED is unchanged)
#define OFF_HIST  ((size_t)0)                                   // 2,097,152 (unused)
#define OFF_BOFF  (OFF_HIST + (size_t)NBATCH*HB*BINS*2)         // 8*2048*4 = 65,536
#define OFF_BCNT  (OFF_BOFF + (size_t)NBATCH*BINS*4)            // 65,536 (hist accumulator)
#define OFF_CTR   (OFF_BCNT + (size_t)NBATCH*BINS*4)            // cbin(32)+pcnt(1024)+binpos(65536)
#define CTR_BYTES ((size_t)(32 + NBATCH*PCHUNK*4 + NBATCH*BINS*4))
#define OFF_CAND  (OFF_CTR + 66624)                             // 8*8192*8 = 524,288
#define OFF_BOXES (OFF_CAND + (size_t)NBATCH*CAND_CAP*8)        // 8*6000*16 = 768,000
#define OFF_PAIRS (OFF_BOXES + (size_t)NBATCH*PRE_NMS*16)       // 8*32*256*4 = 262,144
#define WS_NEEDED (OFF_PAIRS + (size_t)NBATCH*PCHUNK*PCAP*4)

__device__ __forceinline__ unsigned score_bin(float s) {
    int b = (int)(s * (float)BINS);
    if (b < 0) b = 0;
    if (b > BINS - 1) b = BINS - 1;
    return (unsigned)b;
}

// K1: per-block private LDS histogram of scores[b,:,1], then atomicAdd into
// global bcnt[b][bin] (zeroed beforehand). No intermediate hist buffer.
__global__ __launch_bounds__(256) void k_hist(const float* __restrict__ scores,
                                              uint32_t* __restrict__ bcnt) {
    __shared__ uint32_t lh[BINS];
    const int b = blockIdx.y;
    for (int t = threadIdx.x; t < BINS; t += 256) lh[t] = 0;
    __syncthreads();
    const float4* s4 = reinterpret_cast<const float4*>(scores) + (size_t)b * (NA / 2);
    const int n4 = NA / 2;
    const int stride = gridDim.x * 256;
    for (int i = blockIdx.x * 256 + threadIdx.x; i < n4; i += stride) {
        float4 v = s4[i];
        atomicAdd(&lh[score_bin(v.y)], 1u);
        atomicAdd(&lh[score_bin(v.w)], 1u);
    }
    __syncthreads();
    for (int t = threadIdx.x; t < BINS; t += 256) {
        uint32_t v = lh[t];
        if (v) atomicAdd(&bcnt[(size_t)b * BINS + t], v);
    }
}

// K2: per-batch suffix offsets (descending bins) + threshold bin C, from bcnt.
__global__ __launch_bounds__(256) void k_thresh2(const uint32_t* __restrict__ bcnt,
                                                 uint32_t* __restrict__ boff,
                                                 uint32_t* __restrict__ cbin) {
    __shared__ uint32_t hsum[BINS];
    __shared__ uint32_t csum[256];
    __shared__ int sC;
    const int b = blockIdx.x;
    const int t = threadIdx.x;
    if (t == 0) sC = 0;
    for (int p = t; p < BINS; p += 256) hsum[p] = bcnt[(size_t)b * BINS + p];
    __syncthreads();
    {
        uint32_t c = 0;
        for (int q = 0; q < 8; ++q) c += hsum[t * 8 + q];
        csum[t] = c;
    }
    __syncthreads();
    if (t == 0) {             // suffix over 256 chunk sums (descending)
        uint32_t suf = 0;
        for (int c = 255; c >= 0; --c) { uint32_t v = csum[c]; csum[c] = suf; suf += v; }
    }
    __syncthreads();
    uint32_t acc = csum[t];   // keys in bins above this chunk
    for (int q = 7; q >= 0; --q) {
        int bin = t * 8 + q;
        uint32_t h = hsum[bin];
        boff[(size_t)b * BINS + bin] = acc;   // # keys in bins > bin
        if (acc + h >= PRE_NMS) atomicMax(&sC, bin);
        acc += h;
    }
    __syncthreads();
    if (t == 0) cbin[b] = (uint32_t)sC;
}

// K3: gather keys (bin >= C) into bin-partitioned slots via LDS block aggregation.
// key = (score_bits<<32) | ~index  (descending key order == score desc, index asc)
__global__ __launch_bounds__(256) void k_gather(const float* __restrict__ scores,
                                                const uint32_t* __restrict__ cbin,
                                                const uint32_t* __restrict__ boff,
                                                uint32_t* __restrict__ binpos,
                                                uint64_t* __restrict__ cand) {
    __shared__ uint64_t keybuf[GBUF];
    __shared__ uint16_t binbuf[GBUF];
    __shared__ uint32_t bcnts[BINS];
    __shared__ uint32_t gbase[BINS];
    __shared__ uint32_t nbuf;
    const int b = blockIdx.y;
    const unsigned C = cbin[b];
    for (int t = threadIdx.x; t < BINS; t += 256) bcnts[t] = 0;
    if (threadIdx.x == 0) nbuf = 0;
    __syncthreads();
    const float4* s4 = reinterpret_cast<const float4*>(scores) + (size_t)b * (NA / 2);
    const int n4 = NA / 2;
    const int stride = gridDim.x * 256;
    uint64_t* cb = cand + (size_t)b * CAND_CAP;
    for (int i = blockIdx.x * 256 + threadIdx.x; i < n4; i += stride) {
        float4 v = s4[i];
        float sc[2] = { v.y, v.w };
        #pragma unroll
        for (int h = 0; h < 2; ++h) {
            unsigned bin = score_bin(sc[h]);
            if (bin >= C) {
                unsigned idx = 2u * (unsigned)i + (unsigned)h;
                uint64_t key = ((uint64_t)__float_as_uint(sc[h]) << 32) | (uint32_t)(~idx);
                unsigned p = atomicAdd(&nbuf, 1u);
                if (p < GBUF) {
                    keybuf[p] = key; binbuf[p] = (uint16_t)bin;
                    atomicAdd(&bcnts[bin], 1u);
                } else {  // overflow fallback: direct global placement (slow path, rare)
                    unsigned pos = boff[(size_t)b * BINS + bin] +
                                   atomicAdd(&binpos[(size_t)b * BINS + bin], 1u);
                    if (pos < CAND_CAP) cb[pos] = key;
                }
            }
        }
    }
    __syncthreads();
    for (int t = threadIdx.x; t < BINS; t += 256) {
        uint32_t c = bcnts[t];
        if (c) gbase[t] = boff[(size_t)b * BINS + t] +
                          atomicAdd(&binpos[(size_t)b * BINS + t], c);
        bcnts[t] = 0;   // reuse as intra-bin cursor
    }
    __syncthreads();
    unsigned n = nbuf; if (n > GBUF) n = GBUF;
    for (unsigned p = threadIdx.x; p < n; p += 256) {
        unsigned bn = binbuf[p];
        unsigned pos = gbase[bn] + atomicAdd(&bcnts[bn], 1u);
        if (pos < CAND_CAP) cb[pos] = keybuf[p];
    }
}

// K4: per-(batch,bin) bitonic sort of its segment + FUSED box decode.
// Skips bins whose whole segment lies at rank >= PRE_NMS (dead work before),
// never writes sorted keys back (cand is consumed right here).
__global__ __launch_bounds__(256) void k_binsort(const uint32_t* __restrict__ cbin,
                                                 const uint32_t* __restrict__ boff,
                                                 const uint32_t* __restrict__ bcnt,
                                                 const uint64_t* __restrict__ cand,
                                                 const float* __restrict__ deltas,
                                                 const float* __restrict__ anchors,
                                                 float4* __restrict__ boxesOut) {
    __shared__ uint64_t s[SCAP];   // 16 KB
    const int b = blockIdx.y;
    const unsigned bin = cbin[b] + blockIdx.x;
    if (bin >= BINS) return;
    unsigned cnt = bcnt[(size_t)b * BINS + bin];
    if (cnt == 0) return;
    unsigned start = boff[(size_t)b * BINS + bin];
    if (start >= PRE_NMS) return;      // no rank < PRE_NMS in this segment
    if (start + cnt > CAND_CAP) cnt = CAND_CAP - start;
    if (cnt > SCAP) cnt = SCAP;  // envelope guard (expected ~512/bin)
    unsigned m = 256;            // pow2 window >= cnt, >= blockDim for full lanes
    while (m < cnt) m <<= 1;
    const uint64_t* seg = cand + (size_t)b * CAND_CAP + start;
    for (unsigned i = threadIdx.x; i < m; i += 256)
        s[i] = (i < cnt) ? ~seg[i] : ~0ull;    // ascending ~key == descending key; pad last
    __syncthreads();
    for (unsigned k = 2; k <= m; k <<= 1) {
        for (unsigned j = k >> 1; j > 0; j >>= 1) {
            for (unsigned i = threadIdx.x; i < m; i += 256) {
                unsigned ixj = i ^ j;
                if (ixj > i) {
                    uint64_t a = s[i], c = s[ixj];
                    bool up = ((i & k) == 0);
                    if ((a > c) == up) { s[i] = c; s[ixj] = a; }
                }
            }
            __syncthreads();
        }
    }
    // fused decode: global rank = start + i, only ranks < PRE_NMS matter
    for (unsigned i = threadIdx.x; i < cnt; i += 256) {
        unsigned rank = start + i;
        if (rank >= PRE_NMS) continue;
        unsigned idx = (uint32_t)s[i];          // s = ~key, low 32 = ~(~index) = index
        float4 o = make_float4(0.f, 0.f, 0.f, 0.f);
        if (idx < NA) {
            float4 a = reinterpret_cast<const float4*>(anchors)[idx];
            float4 d = reinterpret_cast<const float4*>(deltas)[(size_t)b * NA + idx];
            float h = a.z - a.x, w = a.w - a.y;
            float cy = a.x + 0.5f * h + (d.x * 0.1f) * h;
            float cx = a.y + 0.5f * w + (d.y * 0.1f) * w;
            h = h * expf(d.z * 0.2f);
            w = w * expf(d.w * 0.2f);
            float y1 = cy - 0.5f * h, x1 = cx - 0.5f * w;
            float y2 = y1 + h,        x2 = x1 + w;
            o.x = fminf(fmaxf(y1, 0.f), 1.f);
            o.y = fminf(fmaxf(x1, 0.f), 1.f);
            o.z = fminf(fmaxf(y2, 0.f), 1.f);
            o.w = fminf(fmaxf(x2, 0.f), 1.f);
        }
        boxesOut[(size_t)b * PRE_NMS + rank] = o;
    }
}

// K6: sparse overlap pairs (i<j, IoU>thr), chunked by j-range (c = j>>8) so the
// resolver can process chunks in ascending-j order. Division-free test:
// inter > S*(ai+aj), S = thr/(1+thr). Sentinels kill bounds checks.
__global__ __launch_bounds__(256) void k_pairs(const float4* __restrict__ boxes,
                                               uint32_t* __restrict__ pcnt,
                                               uint32_t* __restrict__ pairs) {
    const int jb = blockIdx.x;          // j-tile of PTJ
    const int ib = blockIdx.y;          // i-tile of PTI
    const int b  = blockIdx.z;
    const int i0 = ib * PTI;
    const int j0 = jb * PTJ;
    if (i0 > j0 + PTJ - 1) return;      // fully below diagonal: no i<j pairs
    __shared__ float4 bi[PTI];
    __shared__ float  ai[PTI];          // pre-scaled S*area(i)
    const int tid = threadIdx.x;
    const float4* bx = boxes + (size_t)b * PRE_NMS;
    const float S = NMS_THR / (1.0f + NMS_THR);
    if (tid < PTI) {
        int ii = i0 + tid;
        float4 v = (ii < PRE_NMS) ? bx[ii] : make_float4(2.f, 2.f, 2.f, 2.f);
        bi[tid] = v;
        ai[tid] = S * ((v.z - v.x) * (v.w - v.y));
    }
    float4 vj[JR]; float aj[JR];
    #pragma unroll
    for (int r = 0; r < JR; ++r) {
        int j = j0 + r * 256 + tid;
        float4 v = (j < PRE_NMS) ? bx[j] : make_float4(2.f, 2.f, 2.f, 2.f);
        vj[r] = v;
        aj[r] = S * ((v.z - v.x) * (v.w - v.y));
    }
    __syncthreads();
    uint32_t* pc = pcnt + b * PCHUNK;
    uint32_t* pb = pairs + (size_t)b * PCHUNK * PCAP;
    const bool touchesDiag = (i0 + PTI - 1 >= j0);   // uniform over block
    if (touchesDiag) {
        for (int it = 0; it < PTI; ++it) {
            float4 vi = bi[it];
            float air = ai[it];
            unsigned i = (unsigned)(i0 + it);
            #pragma unroll
            for (int r = 0; r < JR; ++r) {
                float ih = fmaxf(fminf(vj[r].z, vi.z) - fmaxf(vj[r].x, vi.x), 0.f);
                float iw = fmaxf(fminf(vj[r].w, vi.w) - fmaxf(vj[r].y, vi.y), 0.f);
                float inter = ih * iw;
                unsigned j = (unsigned)(j0 + r * 256 + tid);
                if (inter > air + aj[r] && i < j) {
                    unsigned c = j >> 8;                 // j-range chunk
                    unsigned pos = atomicAdd(&pc[c], 1u);
                    if (pos < PCAP) pb[(size_t)c * PCAP + pos] = (j << 13) | i;
                }
            }
        }
    } else {
        #pragma unroll 2
        for (int it = 0; it < PTI; ++it) {
            float4 vi = bi[it];
            float air = ai[it];
            #pragma unroll
            for (int r = 0; r < JR; ++r) {
                float ih = fmaxf(fminf(vj[r].z, vi.z) - fmaxf(vj[r].x, vi.x), 0.f);
                float iw = fmaxf(fminf(vj[r].w, vi.w) - fmaxf(vj[r].y, vi.y), 0.f);
                float inter = ih * iw;
                if (inter > air + aj[r]) {
                    unsigned i = (unsigned)(i0 + it);
                    unsigned j = (unsigned)(j0 + r * 256 + tid);
                    unsigned c = j >> 8;                 // j-range chunk
                    unsigned pos = atomicAdd(&pc[c], 1u);
                    if (pos < PCAP) pb[(size_t)c * PCAP + pos] = (j << 13) | i;
                }
            }
        }
    }
}

// K7: chunked Gauss-Seidel greedy-NMS resolve + ranked emit.
// Pairs are chunked by j>>8; i<j always, so when chunk c is processed all
// rej bits for i in chunks < c are FINAL. Cross-chunk contributions go into
// base; the few in-chunk pairs (i>>8 == c) are resolved by a tiny Jacobi
// fixpoint over a 256-bit window. Exact greedy answer (suppression DAG in j).
__global__ __launch_bounds__(256) void k_nms_emit(const uint32_t* __restrict__ pcnt,
                                                  const uint32_t* __restrict__ pairsIn,
                                                  const float4* __restrict__ boxes,
                                                  float4* __restrict__ out) {
    __shared__ uint32_t sp[PCHUNK * PCAP];   // 32 KB
    __shared__ uint32_t cpref[PCHUNK + 1];
    __shared__ uint32_t rejA[REJW], pre[REJW + 1];
    __shared__ uint32_t baseW[8], curW[8], nextW[8];
    __shared__ int changed;
    const int b = blockIdx.x;
    const int tid = threadIdx.x;
    if (tid == 0) {
        unsigned s = 0;
        for (int c = 0; c < PCHUNK; ++c) {
            cpref[c] = s;
            unsigned cc = pcnt[b * PCHUNK + c];
            if (cc > PCAP) cc = PCAP;
            s += cc;
        }
        cpref[PCHUNK] = s;
    }
    for (int t = tid; t < REJW; t += 256) rejA[t] = 0;
    __syncthreads();
    for (int c = 0; c < PCHUNK; ++c) {
        unsigned cnt = cpref[c + 1] - cpref[c];
        for (unsigned k = tid; k < cnt; k += 256)
            sp[cpref[c] + k] = pairsIn[((size_t)b * PCHUNK + c) * PCAP + k];
    }
    __syncthreads();
    const int NCH = (PRE_NMS + 255) >> 8;    // 24 chunks cover j < 6144
    for (int c = 0; c < NCH; ++c) {
        const unsigned lo = cpref[c], hi = cpref[c + 1];
        if (lo == hi) continue;              // uniform: rejA words stay 0
        if (tid == 0) changed = 0;           // reused as "has in-chunk pair" flag
        if (tid < 8) baseW[tid] = 0;
        __syncthreads();
        for (unsigned p = lo + tid; p < hi; p += 256) {
            unsigned u = sp[p];
            unsigned j = u >> 13, i = u & 8191u;
            if ((int)(i >> 8) == c) {
                changed = 1;                 // racy same-value store: fine
            } else if (!((rejA[i >> 5] >> (i & 31)) & 1u)) {
                atomicOr(&baseW[(j >> 5) & 7], 1u << (j & 31));
            }
        }
        __syncthreads();
        const int hasIn = changed;
        if (hasIn) {
            if (tid < 8) curW[tid] = baseW[tid];
            __syncthreads();
            for (int it2 = 0; it2 < 256; ++it2) {
                if (tid == 0) changed = 0;
                if (tid < 8) nextW[tid] = baseW[tid];
                __syncthreads();
                for (unsigned p = lo + tid; p < hi; p += 256) {
                    unsigned u = sp[p];
                    unsigned j = u >> 13, i = u & 8191u;
                    if ((int)(i >> 8) == c &&
                        !((curW[(i >> 5) & 7] >> (i & 31)) & 1u))
                        atomicOr(&nextW[(j >> 5) & 7], 1u << (j & 31));
                }
                __syncthreads();
                if (tid < 8) {
                    if (nextW[tid] != curW[tid]) changed = 1;
                    curW[tid] = nextW[tid];
                }
                __syncthreads();
                if (!changed) break;
            }
            if (tid < 8) rejA[c * 8 + tid] = curW[tid];
        } else {
            if (tid < 8) rejA[c * 8 + tid] = baseW[tid];
        }
        __syncthreads();
    }
    if (tid == 0) {
        unsigned c2 = 0;
        for (int w = 0; w < REJW; ++w) { pre[w] = c2; c2 += __popc(rejA[w]); }
        pre[REJW] = c2;
    }
    __syncthreads();
    const float4* bx = boxes + (size_t)b * PRE_NMS;
    float4* ob = out + (size_t)b * NPROP;
    for (int j = tid; j < PRE_NMS; j += 256) {
        unsigned w = (unsigned)j >> 5, bit = (unsigned)j & 31;
        if ((rejA[w] >> bit) & 1u) continue;
        unsigned rank = (unsigned)j - (pre[w] + __popc(rejA[w] & ((1u << bit) - 1u)));
        if (rank < NPROP) ob[rank] = bx[j];
    }
}

extern "C" void kernel_launch(void* const* d_in, const int* in_sizes, int n_in,
                              void* d_out, int out_size, void* d_ws, size_t ws_size,
                              hipStream_t stream) {
    const float* scores  = (const float*)d_in[0];  // (8, NA, 2)
    const float* deltas  = (const float*)d_in[1];  // (8, NA, 4)
    const float* anchors = (const float*)d_in[2];  // (NA, 4)

    if (ws_size < WS_NEEDED) return;  // fail-safe

    char* ws = (char*)d_ws;
    uint32_t* boff   = (uint32_t*)(ws + OFF_BOFF);
    uint32_t* bcnt   = (uint32_t*)(ws + OFF_BCNT);
    uint32_t* cbin   = (uint32_t*)(ws + OFF_CTR);
    uint32_t* pcnt   = cbin + NBATCH;
    uint32_t* binpos = pcnt + NBATCH * PCHUNK;
    uint64_t* cand   = (uint64_t*)(ws + OFF_CAND);
    float4*   boxes  = (float4*)(ws + OFF_BOXES);
    uint32_t* pairs  = (uint32_t*)(ws + OFF_PAIRS);

    // zero bcnt (hist accumulator) + counters (bcnt..CTR region is contiguous), and output
    hipMemsetAsync((void*)bcnt, 0, (size_t)NBATCH * BINS * 4 + CTR_BYTES, stream);
    hipMemsetAsync(d_out, 0, (size_t)NBATCH * NPROP * 4 * sizeof(float), stream);

    k_hist   <<<dim3(HB, NBATCH), 256, 0, stream>>>(scores, bcnt);
    k_thresh2<<<NBATCH, 256, 0, stream>>>(bcnt, boff, cbin);
    k_gather <<<dim3(GB, NBATCH), 256, 0, stream>>>(scores, cbin, boff, binpos, cand);
    k_binsort<<<dim3(128, NBATCH), 256, 0, stream>>>(cbin, boff, bcnt, cand,
                                                     deltas, anchors, boxes);
    k_pairs  <<<dim3((PRE_NMS + PTJ - 1) / PTJ, (PRE_NMS + PTI - 1) / PTI, NBATCH),
               256, 0, stream>>>(boxes, pcnt, pairs);
    k_nms_emit<<<NBATCH, 256, 0, stream>>>(pcnt, pairs, boxes, (float4*)d_out);
}